// Round 4
// baseline (159.606 us; speedup 1.0000x reference)
//
#include <hip/hip_runtime.h>

// GCN layer: out = D^-1/2 (A + I) D^-1/2 (X W) + b
// N=50000, E=800000, 128 ch. MFMA bf16 GEMM + fused dinv scaling + bf16 gather table.
// R3: replaced atomic count+fill CSR build (52MB write amplification, ~80us) with a
// locality-engineered counting sort: hist -> colscan -> binscatter (contiguous
// per-block runs) -> per-bucket CSR build (one 16KB csr window per CU).

constexpr int CH = 128;
constexpr int CHUNK = 4096;    // edges per binning block
constexpr int NCMAX = 256;     // max coarse buckets (256 nodes each -> N <= 65536)

typedef __attribute__((ext_vector_type(8))) short short8;
typedef __attribute__((ext_vector_type(4))) float f32x4;

static __device__ __forceinline__ ushort f2bf(float f) {
    unsigned u = __float_as_uint(f);
    u += 0x7fff + ((u >> 16) & 1);   // RNE
    return (ushort)(u >> 16);
}

// ---- CSR build: counting sort by destination ----------------------------

// per-block histogram over coarse buckets (dst>>8)
__global__ __launch_bounds__(256) void hist_kernel(const int* __restrict__ dst,
                                                   int* __restrict__ h, int E, int nc) {
    __shared__ int hh[NCMAX];
    int t = threadIdx.x, b = blockIdx.x;
    for (int i = t; i < nc; i += 256) hh[i] = 0;
    __syncthreads();
    int s = b * CHUNK, e = min(E, s + CHUNK);
    for (int i = s + t; i < e; i += 256) atomicAdd(&hh[dst[i] >> 8], 1);
    __syncthreads();
    for (int i = t; i < nc; i += 256) h[b * nc + i] = hh[i];
}

// column-major scan of h (bucket-major over blocks) -> per-(block,bucket) bases
__global__ __launch_bounds__(256) void colscan_kernel(int* __restrict__ h,
        int* __restrict__ bbase, int nblk, int nc) {
    __shared__ int tot[256];
    int t = threadIdx.x;
    int run = 0;
    if (t < nc) {
        for (int j = 0; j < nblk; ++j) {
            int v = h[j * nc + t];
            h[j * nc + t] = run;      // exclusive within column
            run += v;
        }
    }
    tot[t] = (t < nc) ? run : 0;
    __syncthreads();
    #pragma unroll
    for (int d = 1; d < 256; d <<= 1) {
        int v = (t >= d) ? tot[t - d] : 0;
        __syncthreads();
        tot[t] += v;
        __syncthreads();
    }
    int excl = tot[t] - run;          // exclusive bucket base
    if (t < nc) {
        bbase[t] = excl;
        if (t == nc - 1) bbase[nc] = tot[t];   // == E
        for (int j = 0; j < nblk; ++j) h[j * nc + t] += excl;
    }
}

// scatter (src,dst) pairs into bucket-sorted ebuf; each block writes only its
// pre-reserved contiguous runs -> near-1x write amplification, no global atomics
__global__ __launch_bounds__(256) void binscatter_kernel(const int* __restrict__ src,
        const int* __restrict__ dst, const int* __restrict__ h,
        uint2* __restrict__ ebuf, int E, int nc) {
    __shared__ int cur[NCMAX];
    int t = threadIdx.x, b = blockIdx.x;
    for (int i = t; i < nc; i += 256) cur[i] = h[b * nc + i];
    __syncthreads();
    int s = b * CHUNK, e = min(E, s + CHUNK);
    for (int i = s + t; i < e; i += 256) {
        int d = dst[i];
        int pos = atomicAdd(&cur[d >> 8], 1);
        ebuf[pos] = make_uint2((unsigned)src[i], (unsigned)d);
    }
}

// one block per bucket: local 256-node histogram + scan -> off/dinv (coalesced),
// then scatter src into this bucket's contiguous csr window (L2-local on one CU)
__global__ __launch_bounds__(256) void bucket_csr_kernel(const uint2* __restrict__ ebuf,
        const int* __restrict__ bbase, int* __restrict__ off, int* __restrict__ csr,
        float* __restrict__ dinv, int N) {
    __shared__ int hist[256], cur[256], sc[256];
    int t = threadIdx.x, k = blockIdx.x;
    int s = bbase[k], e = bbase[k + 1];
    hist[t] = 0;
    __syncthreads();
    for (int i = s + t; i < e; i += 256) atomicAdd(&hist[ebuf[i].y & 255], 1);
    __syncthreads();
    int v = hist[t];
    sc[t] = v;
    __syncthreads();
    #pragma unroll
    for (int d = 1; d < 256; d <<= 1) {
        int u = (t >= d) ? sc[t - d] : 0;
        __syncthreads();
        sc[t] += u;
        __syncthreads();
    }
    int excl = sc[t] - v;
    int node = k * 256 + t;
    if (node <= N) off[node] = s + excl;   // node==N lands in last bucket -> E
    if (node < N) dinv[node] = rsqrtf((float)(v + 1));   // +1 self loop
    cur[t] = s + excl;
    __syncthreads();
    for (int i = s + t; i < e; i += 256) {
        uint2 u = ebuf[i];
        int pos = atomicAdd(&cur[u.y & 255], 1);
        csr[pos] = (int)u.x;
    }
}

// ---- W pre-pack: fp32 [128][128] -> bf16 transposed, XOR-swizzled -------

__global__ void pack_w(const float* __restrict__ W, ushort* __restrict__ Wp) {
    int tid = blockIdx.x * blockDim.x + threadIdx.x;   // 2048 threads
    if (tid >= 2048) return;
    int col = tid >> 4, chunk = tid & 15;
    ushort tmp[8];
    #pragma unroll
    for (int i = 0; i < 8; ++i)
        tmp[i] = f2bf(W[(size_t)(chunk * 8 + i) * CH + col]);
    int d = col * 16 + (chunk ^ (col & 7));
    *(uint4*)&Wp[(size_t)d * 8] = *(uint4*)tmp;
}

// ---- GEMM: xwd[r][:] = (x[r][:] @ W) * dinv[r], bf16 out ----------------

__global__ __launch_bounds__(256) void gemm_mfma(const float* __restrict__ x,
        const ushort* __restrict__ Wp, const float* __restrict__ dinv,
        ushort* __restrict__ xwd, int N) {
    __shared__ alignas(16) ushort Wlds[16384];   // 32 KB
    int t = threadIdx.x;
    int wv = t >> 6, l = t & 63;
    int c15 = l & 15, kc = l >> 4;               // kc in 0..3
    int row0 = blockIdx.x * 64 + wv * 16;
    int r = row0 + c15;
    bool valid = r < N;

    short8 af[4];
    #pragma unroll
    for (int ks = 0; ks < 4; ++ks) {
        float4 a0 = make_float4(0.f,0.f,0.f,0.f), a1 = a0;
        if (valid) {
            const float* p = x + (size_t)r * CH + ks * 32 + kc * 8;
            a0 = *(const float4*)p;
            a1 = *(const float4*)(p + 4);
        }
        short8 v;
        v[0]=f2bf(a0.x); v[1]=f2bf(a0.y); v[2]=f2bf(a0.z); v[3]=f2bf(a0.w);
        v[4]=f2bf(a1.x); v[5]=f2bf(a1.y); v[6]=f2bf(a1.z); v[7]=f2bf(a1.w);
        af[ks] = v;
    }

    #pragma unroll
    for (int i = 0; i < 8; ++i) {
        int idx = i * 256 + t;
        *(uint4*)&Wlds[idx * 8] = *(const uint4*)&Wp[idx * 8];
    }
    __syncthreads();

    f32x4 acc[8];
    #pragma unroll
    for (int ct = 0; ct < 8; ++ct) { f32x4 z = {0.f,0.f,0.f,0.f}; acc[ct] = z; }

    int swz = l & 7;
    #pragma unroll
    for (int ks = 0; ks < 4; ++ks) {
        #pragma unroll
        for (int ct = 0; ct < 8; ++ct) {
            int col = ct * 16 + c15;
            int idx16 = (col * 16 + ks * 4 + kc) ^ swz;
            short8 bfrag = *(const short8*)&Wlds[idx16 * 8];
            acc[ct] = __builtin_amdgcn_mfma_f32_16x16x32_bf16(af[ks], bfrag, acc[ct], 0, 0, 0);
        }
    }

    float dv[4];
    #pragma unroll
    for (int rr = 0; rr < 4; ++rr) {
        int row = row0 + kc * 4 + rr;
        dv[rr] = (row < N) ? dinv[row] : 0.f;
    }
    __syncthreads();   // all waves done reading Wlds; reuse as bounce buffer

    ushort* bw = Wlds + wv * 2048;   // 16 rows x 128 cols bf16 per wave
    #pragma unroll
    for (int ct = 0; ct < 8; ++ct) {
        #pragma unroll
        for (int rr = 0; rr < 4; ++rr) {
            int row_local = kc * 4 + rr;
            bw[row_local * CH + ct * 16 + c15] = f2bf(acc[ct][rr] * dv[rr]);
        }
    }
    #pragma unroll
    for (int p = 0; p < 4; ++p) {
        int row_local = p * 4 + kc;
        int row = row0 + row_local;
        if (row < N) {
            uint4 vv = *(const uint4*)&bw[row_local * CH + c15 * 8];
            *(uint4*)&xwd[(size_t)row * CH + c15 * 8] = vv;
        }
    }
}

// ---- Aggregation: out[i] = dinv[i] * (sum_j xwd[src_j] + xwd[i]) + b ----

__global__ __launch_bounds__(256) void agg_kernel(const ushort* __restrict__ xwd,
        const int* __restrict__ csr, const int* __restrict__ off,
        const float* __restrict__ dinv, const float* __restrict__ b,
        float* __restrict__ out, int N) {
    int t = threadIdx.x;
    int c15 = t & 15;                      // 16 lanes/node, 8 ch each
    int node = blockIdx.x * 16 + (t >> 4);
    if (node >= N) return;
    int s = off[node], e = off[node + 1];
    float acc[8] = {0.f,0.f,0.f,0.f,0.f,0.f,0.f,0.f};
    const ushort* base = xwd + c15 * 8;

    int sr = (s < e) ? csr[s] : node;
    for (int j = s; j < e; ++j) {
        int nsr = (j + 1 < e) ? csr[j + 1] : node;   // prefetch next index
        uint4 v = *(const uint4*)(base + (size_t)sr * CH);
        acc[0] += __uint_as_float(v.x << 16);
        acc[1] += __uint_as_float(v.x & 0xffff0000u);
        acc[2] += __uint_as_float(v.y << 16);
        acc[3] += __uint_as_float(v.y & 0xffff0000u);
        acc[4] += __uint_as_float(v.z << 16);
        acc[5] += __uint_as_float(v.z & 0xffff0000u);
        acc[6] += __uint_as_float(v.w << 16);
        acc[7] += __uint_as_float(v.w & 0xffff0000u);
        sr = nsr;
    }
    {   // self loop term
        uint4 v = *(const uint4*)(base + (size_t)node * CH);
        acc[0] += __uint_as_float(v.x << 16);
        acc[1] += __uint_as_float(v.x & 0xffff0000u);
        acc[2] += __uint_as_float(v.y << 16);
        acc[3] += __uint_as_float(v.y & 0xffff0000u);
        acc[4] += __uint_as_float(v.z << 16);
        acc[5] += __uint_as_float(v.z & 0xffff0000u);
        acc[6] += __uint_as_float(v.w << 16);
        acc[7] += __uint_as_float(v.w & 0xffff0000u);
    }
    float di = dinv[node];
    float4 b0 = *(const float4*)&b[c15 * 8];
    float4 b1 = *(const float4*)&b[c15 * 8 + 4];
    float4 o0, o1;
    o0.x = di * acc[0] + b0.x;  o0.y = di * acc[1] + b0.y;
    o0.z = di * acc[2] + b0.z;  o0.w = di * acc[3] + b0.w;
    o1.x = di * acc[4] + b1.x;  o1.y = di * acc[5] + b1.y;
    o1.z = di * acc[6] + b1.z;  o1.w = di * acc[7] + b1.w;
    float* op = out + (size_t)node * CH + c15 * 8;
    *(float4*)op = o0;
    *(float4*)(op + 4) = o1;
}

// ---- launch -------------------------------------------------------------

extern "C" void kernel_launch(void* const* d_in, const int* in_sizes, int n_in,
                              void* d_out, int out_size, void* d_ws, size_t ws_size,
                              hipStream_t stream) {
    const float* x  = (const float*)d_in[0];
    const float* Wm = (const float*)d_in[1];
    const float* b  = (const float*)d_in[2];
    const int*   ei = (const int*)d_in[3];
    int N = in_sizes[0] / CH;
    int E = in_sizes[3] / 2;
    const int* src = ei;
    const int* dst = ei + E;
    float* out = (float*)d_out;

    char* w = (char*)d_ws;
    auto alloc = [&](size_t bytes) {
        char* p = w;
        w += (bytes + 255) & ~(size_t)255;
        return p;
    };
    int nc = (N + 255) >> 8;                     // 196 coarse buckets
    int nblk = (E + CHUNK - 1) / CHUNK;          // 196 binning blocks

    ushort* xwd  = (ushort*)alloc((size_t)N * CH * 2);   // 12.8 MB
    uint2*  ebuf = (uint2*)xwd;                          // E*8 = 6.4 MB, dead before gemm
    int*    off  = (int*)alloc((size_t)(N + 1) * 4);
    int*    csr  = (int*)alloc((size_t)E * 4);
    float*  dinv = (float*)alloc((size_t)N * 4);
    ushort* Wp   = (ushort*)alloc((size_t)16384 * 2);
    int*    h    = (int*)alloc((size_t)nblk * nc * 4);
    int*    bbase= (int*)alloc((size_t)(nc + 1) * 4);

    hist_kernel<<<nblk, 256, 0, stream>>>(dst, h, E, nc);
    colscan_kernel<<<1, 256, 0, stream>>>(h, bbase, nblk, nc);
    binscatter_kernel<<<nblk, 256, 0, stream>>>(src, dst, h, ebuf, E, nc);
    bucket_csr_kernel<<<nc, 256, 0, stream>>>(ebuf, bbase, off, csr, dinv, N);
    pack_w<<<8, 256, 0, stream>>>(Wm, Wp);
    gemm_mfma<<<(N + 63) / 64, 256, 0, stream>>>(x, Wp, dinv, xwd, N);
    agg_kernel<<<(N + 15) / 16, 256, 0, stream>>>(xwd, csr, off, dinv, b, out, N);
}

// Round 5
// 94.996 us; speedup vs baseline: 1.6801x; 1.6801x over previous
//
#include <hip/hip_runtime.h>

// GCN layer: out = D^-1/2 (A + I) D^-1/2 (X W) + b
// N=50000, E=800000, 128 ch. MFMA bf16 GEMM + fused dinv scaling + bf16 gather table.
// R3: counting-sort CSR build (hist -> colscan -> binscatter -> bucket CSR).
// R4: colscan was 73us (1 block, serial dependent column walk). Split into
// per-bucket parallel scan blocks + tiny bbase scan; base-add fused into binscatter.

constexpr int CH = 128;
constexpr int CHUNK = 4096;    // edges per binning block
constexpr int NCMAX = 256;     // max coarse buckets (256 nodes each -> N <= 65536)

typedef __attribute__((ext_vector_type(8))) short short8;
typedef __attribute__((ext_vector_type(4))) float f32x4;

static __device__ __forceinline__ ushort f2bf(float f) {
    unsigned u = __float_as_uint(f);
    u += 0x7fff + ((u >> 16) & 1);   // RNE
    return (ushort)(u >> 16);
}

// ---- CSR build: counting sort by destination ----------------------------

// per-block histogram over coarse buckets (dst>>8); h[b*nc + i]
__global__ __launch_bounds__(256) void hist_kernel(const int* __restrict__ dst,
                                                   int* __restrict__ h, int E, int nc) {
    __shared__ int hh[NCMAX];
    int t = threadIdx.x, b = blockIdx.x;
    for (int i = t; i < nc; i += 256) hh[i] = 0;
    __syncthreads();
    int s = b * CHUNK, e = min(E, s + CHUNK);
    for (int i = s + t; i < e; i += 256) atomicAdd(&hh[dst[i] >> 8], 1);
    __syncthreads();
    for (int i = t; i < nc; i += 256) h[b * nc + i] = hh[i];
}

// one block per bucket: parallel scan down the column h[:, i] -> exclusive
// within-column prefix (written back in place), column total -> coltot[i]
__global__ __launch_bounds__(256) void colscan_cols(int* __restrict__ h,
        int* __restrict__ coltot, int nblk, int nc) {
    __shared__ int sm[256];
    int i = blockIdx.x;      // bucket
    int t = threadIdx.x;     // block index j
    int v = (t < nblk) ? h[t * nc + i] : 0;
    sm[t] = v;
    __syncthreads();
    #pragma unroll
    for (int d = 1; d < 256; d <<= 1) {
        int u = (t >= d) ? sm[t - d] : 0;
        __syncthreads();
        sm[t] += u;
        __syncthreads();
    }
    if (t < nblk) h[t * nc + i] = sm[t] - v;   // exclusive (bucket base added later)
    if (t == 255) coltot[i] = sm[255];
}

// scan the nc column totals -> bucket bases; bbase[nc] = E
__global__ __launch_bounds__(256) void scan_bbase(const int* __restrict__ coltot,
        int* __restrict__ bbase, int nc) {
    __shared__ int sm[256];
    int t = threadIdx.x;
    int v = (t < nc) ? coltot[t] : 0;
    sm[t] = v;
    __syncthreads();
    #pragma unroll
    for (int d = 1; d < 256; d <<= 1) {
        int u = (t >= d) ? sm[t - d] : 0;
        __syncthreads();
        sm[t] += u;
        __syncthreads();
    }
    if (t < nc) bbase[t] = sm[t] - v;
    if (t == nc - 1) bbase[nc] = sm[t];   // == E
}

// scatter (src,dst) pairs into bucket-sorted ebuf; each block writes only its
// pre-reserved contiguous runs -> near-1x write amplification, no global atomics
__global__ __launch_bounds__(256) void binscatter_kernel(const int* __restrict__ src,
        const int* __restrict__ dst, const int* __restrict__ h,
        const int* __restrict__ bbase, uint2* __restrict__ ebuf, int E, int nc) {
    __shared__ int cur[NCMAX];
    int t = threadIdx.x, b = blockIdx.x;
    for (int i = t; i < nc; i += 256) cur[i] = h[b * nc + i] + bbase[i];
    __syncthreads();
    int s = b * CHUNK, e = min(E, s + CHUNK);
    for (int i = s + t; i < e; i += 256) {
        int d = dst[i];
        int pos = atomicAdd(&cur[d >> 8], 1);
        ebuf[pos] = make_uint2((unsigned)src[i], (unsigned)d);
    }
}

// one block per bucket: local 256-node histogram + scan -> off/dinv (coalesced),
// then scatter src into this bucket's contiguous csr window (L2-local on one CU)
__global__ __launch_bounds__(256) void bucket_csr_kernel(const uint2* __restrict__ ebuf,
        const int* __restrict__ bbase, int* __restrict__ off, int* __restrict__ csr,
        float* __restrict__ dinv, int N) {
    __shared__ int hist[256], cur[256], sc[256];
    int t = threadIdx.x, k = blockIdx.x;
    int s = bbase[k], e = bbase[k + 1];
    hist[t] = 0;
    __syncthreads();
    for (int i = s + t; i < e; i += 256) atomicAdd(&hist[ebuf[i].y & 255], 1);
    __syncthreads();
    int v = hist[t];
    sc[t] = v;
    __syncthreads();
    #pragma unroll
    for (int d = 1; d < 256; d <<= 1) {
        int u = (t >= d) ? sc[t - d] : 0;
        __syncthreads();
        sc[t] += u;
        __syncthreads();
    }
    int excl = sc[t] - v;
    int node = k * 256 + t;
    if (node <= N) off[node] = s + excl;   // node==N lands in last bucket -> E
    if (node < N) dinv[node] = rsqrtf((float)(v + 1));   // +1 self loop
    cur[t] = s + excl;
    __syncthreads();
    for (int i = s + t; i < e; i += 256) {
        uint2 u = ebuf[i];
        int pos = atomicAdd(&cur[u.y & 255], 1);
        csr[pos] = (int)u.x;
    }
}

// ---- W pre-pack: fp32 [128][128] -> bf16 transposed, XOR-swizzled -------

__global__ void pack_w(const float* __restrict__ W, ushort* __restrict__ Wp) {
    int tid = blockIdx.x * blockDim.x + threadIdx.x;   // 2048 threads
    if (tid >= 2048) return;
    int col = tid >> 4, chunk = tid & 15;
    ushort tmp[8];
    #pragma unroll
    for (int i = 0; i < 8; ++i)
        tmp[i] = f2bf(W[(size_t)(chunk * 8 + i) * CH + col]);
    int d = col * 16 + (chunk ^ (col & 7));
    *(uint4*)&Wp[(size_t)d * 8] = *(uint4*)tmp;
}

// ---- GEMM: xwd[r][:] = (x[r][:] @ W) * dinv[r], bf16 out ----------------

__global__ __launch_bounds__(256) void gemm_mfma(const float* __restrict__ x,
        const ushort* __restrict__ Wp, const float* __restrict__ dinv,
        ushort* __restrict__ xwd, int N) {
    __shared__ alignas(16) ushort Wlds[16384];   // 32 KB
    int t = threadIdx.x;
    int wv = t >> 6, l = t & 63;
    int c15 = l & 15, kc = l >> 4;               // kc in 0..3
    int row0 = blockIdx.x * 64 + wv * 16;
    int r = row0 + c15;
    bool valid = r < N;

    short8 af[4];
    #pragma unroll
    for (int ks = 0; ks < 4; ++ks) {
        float4 a0 = make_float4(0.f,0.f,0.f,0.f), a1 = a0;
        if (valid) {
            const float* p = x + (size_t)r * CH + ks * 32 + kc * 8;
            a0 = *(const float4*)p;
            a1 = *(const float4*)(p + 4);
        }
        short8 v;
        v[0]=f2bf(a0.x); v[1]=f2bf(a0.y); v[2]=f2bf(a0.z); v[3]=f2bf(a0.w);
        v[4]=f2bf(a1.x); v[5]=f2bf(a1.y); v[6]=f2bf(a1.z); v[7]=f2bf(a1.w);
        af[ks] = v;
    }

    #pragma unroll
    for (int i = 0; i < 8; ++i) {
        int idx = i * 256 + t;
        *(uint4*)&Wlds[idx * 8] = *(const uint4*)&Wp[idx * 8];
    }
    __syncthreads();

    f32x4 acc[8];
    #pragma unroll
    for (int ct = 0; ct < 8; ++ct) { f32x4 z = {0.f,0.f,0.f,0.f}; acc[ct] = z; }

    int swz = l & 7;
    #pragma unroll
    for (int ks = 0; ks < 4; ++ks) {
        #pragma unroll
        for (int ct = 0; ct < 8; ++ct) {
            int col = ct * 16 + c15;
            int idx16 = (col * 16 + ks * 4 + kc) ^ swz;
            short8 bfrag = *(const short8*)&Wlds[idx16 * 8];
            acc[ct] = __builtin_amdgcn_mfma_f32_16x16x32_bf16(af[ks], bfrag, acc[ct], 0, 0, 0);
        }
    }

    float dv[4];
    #pragma unroll
    for (int rr = 0; rr < 4; ++rr) {
        int row = row0 + kc * 4 + rr;
        dv[rr] = (row < N) ? dinv[row] : 0.f;
    }
    __syncthreads();   // all waves done reading Wlds; reuse as bounce buffer

    ushort* bw = Wlds + wv * 2048;   // 16 rows x 128 cols bf16 per wave
    #pragma unroll
    for (int ct = 0; ct < 8; ++ct) {
        #pragma unroll
        for (int rr = 0; rr < 4; ++rr) {
            int row_local = kc * 4 + rr;
            bw[row_local * CH + ct * 16 + c15] = f2bf(acc[ct][rr] * dv[rr]);
        }
    }
    #pragma unroll
    for (int p = 0; p < 4; ++p) {
        int row_local = p * 4 + kc;
        int row = row0 + row_local;
        if (row < N) {
            uint4 vv = *(const uint4*)&bw[row_local * CH + c15 * 8];
            *(uint4*)&xwd[(size_t)row * CH + c15 * 8] = vv;
        }
    }
}

// ---- Aggregation: out[i] = dinv[i] * (sum_j xwd[src_j] + xwd[i]) + b ----

__global__ __launch_bounds__(256) void agg_kernel(const ushort* __restrict__ xwd,
        const int* __restrict__ csr, const int* __restrict__ off,
        const float* __restrict__ dinv, const float* __restrict__ b,
        float* __restrict__ out, int N) {
    int t = threadIdx.x;
    int c15 = t & 15;                      // 16 lanes/node, 8 ch each
    int node = blockIdx.x * 16 + (t >> 4);
    if (node >= N) return;
    int s = off[node], e = off[node + 1];
    float acc[8] = {0.f,0.f,0.f,0.f,0.f,0.f,0.f,0.f};
    const ushort* base = xwd + c15 * 8;

    int sr = (s < e) ? csr[s] : node;
    for (int j = s; j < e; ++j) {
        int nsr = (j + 1 < e) ? csr[j + 1] : node;   // prefetch next index
        uint4 v = *(const uint4*)(base + (size_t)sr * CH);
        acc[0] += __uint_as_float(v.x << 16);
        acc[1] += __uint_as_float(v.x & 0xffff0000u);
        acc[2] += __uint_as_float(v.y << 16);
        acc[3] += __uint_as_float(v.y & 0xffff0000u);
        acc[4] += __uint_as_float(v.z << 16);
        acc[5] += __uint_as_float(v.z & 0xffff0000u);
        acc[6] += __uint_as_float(v.w << 16);
        acc[7] += __uint_as_float(v.w & 0xffff0000u);
        sr = nsr;
    }
    {   // self loop term
        uint4 v = *(const uint4*)(base + (size_t)node * CH);
        acc[0] += __uint_as_float(v.x << 16);
        acc[1] += __uint_as_float(v.x & 0xffff0000u);
        acc[2] += __uint_as_float(v.y << 16);
        acc[3] += __uint_as_float(v.y & 0xffff0000u);
        acc[4] += __uint_as_float(v.z << 16);
        acc[5] += __uint_as_float(v.z & 0xffff0000u);
        acc[6] += __uint_as_float(v.w << 16);
        acc[7] += __uint_as_float(v.w & 0xffff0000u);
    }
    float di = dinv[node];
    float4 b0 = *(const float4*)&b[c15 * 8];
    float4 b1 = *(const float4*)&b[c15 * 8 + 4];
    float4 o0, o1;
    o0.x = di * acc[0] + b0.x;  o0.y = di * acc[1] + b0.y;
    o0.z = di * acc[2] + b0.z;  o0.w = di * acc[3] + b0.w;
    o1.x = di * acc[4] + b1.x;  o1.y = di * acc[5] + b1.y;
    o1.z = di * acc[6] + b1.z;  o1.w = di * acc[7] + b1.w;
    float* op = out + (size_t)node * CH + c15 * 8;
    *(float4*)op = o0;
    *(float4*)(op + 4) = o1;
}

// ---- launch -------------------------------------------------------------

extern "C" void kernel_launch(void* const* d_in, const int* in_sizes, int n_in,
                              void* d_out, int out_size, void* d_ws, size_t ws_size,
                              hipStream_t stream) {
    const float* x  = (const float*)d_in[0];
    const float* Wm = (const float*)d_in[1];
    const float* b  = (const float*)d_in[2];
    const int*   ei = (const int*)d_in[3];
    int N = in_sizes[0] / CH;
    int E = in_sizes[3] / 2;
    const int* src = ei;
    const int* dst = ei + E;
    float* out = (float*)d_out;

    char* w = (char*)d_ws;
    auto alloc = [&](size_t bytes) {
        char* p = w;
        w += (bytes + 255) & ~(size_t)255;
        return p;
    };
    int nc = (N + 255) >> 8;                     // 196 coarse buckets
    int nblk = (E + CHUNK - 1) / CHUNK;          // 196 binning blocks

    ushort* xwd  = (ushort*)alloc((size_t)N * CH * 2);   // 12.8 MB
    uint2*  ebuf = (uint2*)xwd;                          // E*8 = 6.4 MB, dead before gemm
    int*    off  = (int*)alloc((size_t)(N + 1) * 4);
    int*    csr  = (int*)alloc((size_t)E * 4);
    float*  dinv = (float*)alloc((size_t)N * 4);
    ushort* Wp   = (ushort*)alloc((size_t)16384 * 2);
    int*    h    = (int*)alloc((size_t)nblk * nc * 4);
    int*    bbase= (int*)alloc((size_t)(nc + 1) * 4);
    int*    coltot=(int*)alloc((size_t)nc * 4);

    hist_kernel<<<nblk, 256, 0, stream>>>(dst, h, E, nc);
    colscan_cols<<<nc, 256, 0, stream>>>(h, coltot, nblk, nc);
    scan_bbase<<<1, 256, 0, stream>>>(coltot, bbase, nc);
    binscatter_kernel<<<nblk, 256, 0, stream>>>(src, dst, h, bbase, ebuf, E, nc);
    bucket_csr_kernel<<<nc, 256, 0, stream>>>(ebuf, bbase, off, csr, dinv, N);
    pack_w<<<8, 256, 0, stream>>>(Wm, Wp);
    gemm_mfma<<<(N + 63) / 64, 256, 0, stream>>>(x, Wp, dinv, xwd, N);
    agg_kernel<<<(N + 15) / 16, 256, 0, stream>>>(xwd, csr, off, dinv, b, out, N);
}

// Round 6
// 83.430 us; speedup vs baseline: 1.9130x; 1.1386x over previous
//
#include <hip/hip_runtime.h>

// GCN layer: out = D^-1/2 (A + I) D^-1/2 (X W) + b
// N=50000, E=800000, 128 ch. MFMA bf16 GEMM + fused dinv scaling + bf16 gather table.
// R3: counting-sort CSR build (hist -> colscan -> binscatter -> bucket CSR).
// R4: parallel colscan (was 73us single-block serial).
// R5: agg unroll-4 independent gathers (was MLP-1 latency-serialized, 41us);
//     ebuf packed to 4B (src:16 | dst&255:16), csr as ushort (N < 65536).

constexpr int CH = 128;
constexpr int CHUNK = 4096;    // edges per binning block
constexpr int NCMAX = 256;     // max coarse buckets (256 nodes each -> N <= 65536)

typedef __attribute__((ext_vector_type(8))) short short8;
typedef __attribute__((ext_vector_type(4))) float f32x4;

static __device__ __forceinline__ ushort f2bf(float f) {
    unsigned u = __float_as_uint(f);
    u += 0x7fff + ((u >> 16) & 1);   // RNE
    return (ushort)(u >> 16);
}

// ---- CSR build: counting sort by destination ----------------------------

__global__ __launch_bounds__(256) void hist_kernel(const int* __restrict__ dst,
                                                   int* __restrict__ h, int E, int nc) {
    __shared__ int hh[NCMAX];
    int t = threadIdx.x, b = blockIdx.x;
    for (int i = t; i < nc; i += 256) hh[i] = 0;
    __syncthreads();
    int s = b * CHUNK, e = min(E, s + CHUNK);
    for (int i = s + t; i < e; i += 256) atomicAdd(&hh[dst[i] >> 8], 1);
    __syncthreads();
    for (int i = t; i < nc; i += 256) h[b * nc + i] = hh[i];
}

// one block per bucket: parallel scan down column h[:, i]
__global__ __launch_bounds__(256) void colscan_cols(int* __restrict__ h,
        int* __restrict__ coltot, int nblk, int nc) {
    __shared__ int sm[256];
    int i = blockIdx.x;
    int t = threadIdx.x;
    int v = (t < nblk) ? h[t * nc + i] : 0;
    sm[t] = v;
    __syncthreads();
    #pragma unroll
    for (int d = 1; d < 256; d <<= 1) {
        int u = (t >= d) ? sm[t - d] : 0;
        __syncthreads();
        sm[t] += u;
        __syncthreads();
    }
    if (t < nblk) h[t * nc + i] = sm[t] - v;
    if (t == 255) coltot[i] = sm[255];
}

__global__ __launch_bounds__(256) void scan_bbase(const int* __restrict__ coltot,
        int* __restrict__ bbase, int nc) {
    __shared__ int sm[256];
    int t = threadIdx.x;
    int v = (t < nc) ? coltot[t] : 0;
    sm[t] = v;
    __syncthreads();
    #pragma unroll
    for (int d = 1; d < 256; d <<= 1) {
        int u = (t >= d) ? sm[t - d] : 0;
        __syncthreads();
        sm[t] += u;
        __syncthreads();
    }
    if (t < nc) bbase[t] = sm[t] - v;
    if (t == nc - 1) bbase[nc] = sm[t];   // == E
}

// scatter packed (src | (dst&255)<<16) into bucket-sorted ebuf
__global__ __launch_bounds__(256) void binscatter_kernel(const int* __restrict__ src,
        const int* __restrict__ dst, const int* __restrict__ h,
        const int* __restrict__ bbase, unsigned* __restrict__ ebuf, int E, int nc) {
    __shared__ int cur[NCMAX];
    int t = threadIdx.x, b = blockIdx.x;
    for (int i = t; i < nc; i += 256) cur[i] = h[b * nc + i] + bbase[i];
    __syncthreads();
    int s = b * CHUNK, e = min(E, s + CHUNK);
    for (int i = s + t; i < e; i += 256) {
        int d = dst[i];
        int pos = atomicAdd(&cur[d >> 8], 1);
        ebuf[pos] = (unsigned)src[i] | ((unsigned)(d & 255) << 16);
    }
}

// one block per bucket: local histogram + scan -> off/dinv, scatter src (ushort)
__global__ __launch_bounds__(256) void bucket_csr_kernel(const unsigned* __restrict__ ebuf,
        const int* __restrict__ bbase, int* __restrict__ off, ushort* __restrict__ csr,
        float* __restrict__ dinv, int N) {
    __shared__ int hist[256], cur[256], sc[256];
    int t = threadIdx.x, k = blockIdx.x;
    int s = bbase[k], e = bbase[k + 1];
    hist[t] = 0;
    __syncthreads();
    for (int i = s + t; i < e; i += 256) atomicAdd(&hist[(ebuf[i] >> 16) & 255], 1);
    __syncthreads();
    int v = hist[t];
    sc[t] = v;
    __syncthreads();
    #pragma unroll
    for (int d = 1; d < 256; d <<= 1) {
        int u = (t >= d) ? sc[t - d] : 0;
        __syncthreads();
        sc[t] += u;
        __syncthreads();
    }
    int excl = sc[t] - v;
    int node = k * 256 + t;
    if (node <= N) off[node] = s + excl;
    if (node < N) dinv[node] = rsqrtf((float)(v + 1));   // +1 self loop
    cur[t] = s + excl;
    __syncthreads();
    for (int i = s + t; i < e; i += 256) {
        unsigned u = ebuf[i];
        int pos = atomicAdd(&cur[(u >> 16) & 255], 1);
        csr[pos] = (ushort)(u & 0xffffu);
    }
}

// ---- W pre-pack: fp32 [128][128] -> bf16 transposed, XOR-swizzled -------

__global__ void pack_w(const float* __restrict__ W, ushort* __restrict__ Wp) {
    int tid = blockIdx.x * blockDim.x + threadIdx.x;   // 2048 threads
    if (tid >= 2048) return;
    int col = tid >> 4, chunk = tid & 15;
    ushort tmp[8];
    #pragma unroll
    for (int i = 0; i < 8; ++i)
        tmp[i] = f2bf(W[(size_t)(chunk * 8 + i) * CH + col]);
    int d = col * 16 + (chunk ^ (col & 7));
    *(uint4*)&Wp[(size_t)d * 8] = *(uint4*)tmp;
}

// ---- GEMM: xwd[r][:] = (x[r][:] @ W) * dinv[r], bf16 out ----------------

__global__ __launch_bounds__(256) void gemm_mfma(const float* __restrict__ x,
        const ushort* __restrict__ Wp, const float* __restrict__ dinv,
        ushort* __restrict__ xwd, int N) {
    __shared__ alignas(16) ushort Wlds[16384];   // 32 KB
    int t = threadIdx.x;
    int wv = t >> 6, l = t & 63;
    int c15 = l & 15, kc = l >> 4;               // kc in 0..3
    int row0 = blockIdx.x * 64 + wv * 16;
    int r = row0 + c15;
    bool valid = r < N;

    short8 af[4];
    #pragma unroll
    for (int ks = 0; ks < 4; ++ks) {
        float4 a0 = make_float4(0.f,0.f,0.f,0.f), a1 = a0;
        if (valid) {
            const float* p = x + (size_t)r * CH + ks * 32 + kc * 8;
            a0 = *(const float4*)p;
            a1 = *(const float4*)(p + 4);
        }
        short8 v;
        v[0]=f2bf(a0.x); v[1]=f2bf(a0.y); v[2]=f2bf(a0.z); v[3]=f2bf(a0.w);
        v[4]=f2bf(a1.x); v[5]=f2bf(a1.y); v[6]=f2bf(a1.z); v[7]=f2bf(a1.w);
        af[ks] = v;
    }

    #pragma unroll
    for (int i = 0; i < 8; ++i) {
        int idx = i * 256 + t;
        *(uint4*)&Wlds[idx * 8] = *(const uint4*)&Wp[idx * 8];
    }
    __syncthreads();

    f32x4 acc[8];
    #pragma unroll
    for (int ct = 0; ct < 8; ++ct) { f32x4 z = {0.f,0.f,0.f,0.f}; acc[ct] = z; }

    int swz = l & 7;
    #pragma unroll
    for (int ks = 0; ks < 4; ++ks) {
        #pragma unroll
        for (int ct = 0; ct < 8; ++ct) {
            int col = ct * 16 + c15;
            int idx16 = (col * 16 + ks * 4 + kc) ^ swz;
            short8 bfrag = *(const short8*)&Wlds[idx16 * 8];
            acc[ct] = __builtin_amdgcn_mfma_f32_16x16x32_bf16(af[ks], bfrag, acc[ct], 0, 0, 0);
        }
    }

    float dv[4];
    #pragma unroll
    for (int rr = 0; rr < 4; ++rr) {
        int row = row0 + kc * 4 + rr;
        dv[rr] = (row < N) ? dinv[row] : 0.f;
    }
    __syncthreads();   // all waves done reading Wlds; reuse as bounce buffer

    ushort* bw = Wlds + wv * 2048;   // 16 rows x 128 cols bf16 per wave
    #pragma unroll
    for (int ct = 0; ct < 8; ++ct) {
        #pragma unroll
        for (int rr = 0; rr < 4; ++rr) {
            int row_local = kc * 4 + rr;
            bw[row_local * CH + ct * 16 + c15] = f2bf(acc[ct][rr] * dv[rr]);
        }
    }
    #pragma unroll
    for (int p = 0; p < 4; ++p) {
        int row_local = p * 4 + kc;
        int row = row0 + row_local;
        if (row < N) {
            uint4 vv = *(const uint4*)&bw[row_local * CH + c15 * 8];
            *(uint4*)&xwd[(size_t)row * CH + c15 * 8] = vv;
        }
    }
}

// ---- Aggregation: out[i] = dinv[i] * (sum_j xwd[src_j] + xwd[i]) + b ----
// unroll-4: independent index loads + 4 concurrent 16B gathers per lane (MLP=4)

#define ACC8(v)                                    \
    acc[0] += __uint_as_float((v).x << 16);        \
    acc[1] += __uint_as_float((v).x & 0xffff0000u);\
    acc[2] += __uint_as_float((v).y << 16);        \
    acc[3] += __uint_as_float((v).y & 0xffff0000u);\
    acc[4] += __uint_as_float((v).z << 16);        \
    acc[5] += __uint_as_float((v).z & 0xffff0000u);\
    acc[6] += __uint_as_float((v).w << 16);        \
    acc[7] += __uint_as_float((v).w & 0xffff0000u);

__global__ __launch_bounds__(256) void agg_kernel(const ushort* __restrict__ xwd,
        const ushort* __restrict__ csr, const int* __restrict__ off,
        const float* __restrict__ dinv, const float* __restrict__ b,
        float* __restrict__ out, int N) {
    int t = threadIdx.x;
    int c15 = t & 15;                      // 16 lanes/node, 8 ch each
    int node = blockIdx.x * 16 + (t >> 4);
    if (node >= N) return;
    int s = off[node], e = off[node + 1];
    float acc[8] = {0.f,0.f,0.f,0.f,0.f,0.f,0.f,0.f};
    const ushort* base = xwd + c15 * 8;

    int j = s;
    for (; j + 4 <= e; j += 4) {
        int i0 = csr[j], i1 = csr[j + 1], i2 = csr[j + 2], i3 = csr[j + 3];
        uint4 v0 = *(const uint4*)(base + (size_t)i0 * CH);
        uint4 v1 = *(const uint4*)(base + (size_t)i1 * CH);
        uint4 v2 = *(const uint4*)(base + (size_t)i2 * CH);
        uint4 v3 = *(const uint4*)(base + (size_t)i3 * CH);
        ACC8(v0); ACC8(v1); ACC8(v2); ACC8(v3);
    }
    for (; j < e; ++j) {
        int i0 = csr[j];
        uint4 v = *(const uint4*)(base + (size_t)i0 * CH);
        ACC8(v);
    }
    {   // self loop term
        uint4 v = *(const uint4*)(base + (size_t)node * CH);
        ACC8(v);
    }
    float di = dinv[node];
    float4 b0 = *(const float4*)&b[c15 * 8];
    float4 b1 = *(const float4*)&b[c15 * 8 + 4];
    float4 o0, o1;
    o0.x = di * acc[0] + b0.x;  o0.y = di * acc[1] + b0.y;
    o0.z = di * acc[2] + b0.z;  o0.w = di * acc[3] + b0.w;
    o1.x = di * acc[4] + b1.x;  o1.y = di * acc[5] + b1.y;
    o1.z = di * acc[6] + b1.z;  o1.w = di * acc[7] + b1.w;
    float* op = out + (size_t)node * CH + c15 * 8;
    *(float4*)op = o0;
    *(float4*)(op + 4) = o1;
}

// ---- launch -------------------------------------------------------------

extern "C" void kernel_launch(void* const* d_in, const int* in_sizes, int n_in,
                              void* d_out, int out_size, void* d_ws, size_t ws_size,
                              hipStream_t stream) {
    const float* x  = (const float*)d_in[0];
    const float* Wm = (const float*)d_in[1];
    const float* b  = (const float*)d_in[2];
    const int*   ei = (const int*)d_in[3];
    int N = in_sizes[0] / CH;
    int E = in_sizes[3] / 2;
    const int* src = ei;
    const int* dst = ei + E;
    float* out = (float*)d_out;

    char* w = (char*)d_ws;
    auto alloc = [&](size_t bytes) {
        char* p = w;
        w += (bytes + 255) & ~(size_t)255;
        return p;
    };
    int nc = (N + 255) >> 8;                     // 196 coarse buckets
    int nblk = (E + CHUNK - 1) / CHUNK;          // 196 binning blocks

    ushort*   xwd  = (ushort*)alloc((size_t)N * CH * 2);   // 12.8 MB
    unsigned* ebuf = (unsigned*)xwd;                       // E*4 = 3.2 MB, dead before gemm
    int*      off  = (int*)alloc((size_t)(N + 1) * 4);
    ushort*   csr  = (ushort*)alloc((size_t)E * 2);
    float*    dinv = (float*)alloc((size_t)N * 4);
    ushort*   Wp   = (ushort*)alloc((size_t)16384 * 2);
    int*      h    = (int*)alloc((size_t)nblk * nc * 4);
    int*      bbase= (int*)alloc((size_t)(nc + 1) * 4);
    int*      coltot=(int*)alloc((size_t)nc * 4);

    hist_kernel<<<nblk, 256, 0, stream>>>(dst, h, E, nc);
    colscan_cols<<<nc, 256, 0, stream>>>(h, coltot, nblk, nc);
    scan_bbase<<<1, 256, 0, stream>>>(coltot, bbase, nc);
    binscatter_kernel<<<nblk, 256, 0, stream>>>(src, dst, h, bbase, ebuf, E, nc);
    bucket_csr_kernel<<<nc, 256, 0, stream>>>(ebuf, bbase, off, csr, dinv, N);
    pack_w<<<8, 256, 0, stream>>>(Wm, Wp);
    gemm_mfma<<<(N + 63) / 64, 256, 0, stream>>>(x, Wp, dinv, xwd, N);
    agg_kernel<<<(N + 15) / 16, 256, 0, stream>>>(xwd, csr, off, dinv, b, out, N);
}